// Round 4
// baseline (204.286 us; speedup 1.0000x reference)
//
#include <hip/hip_runtime.h>
#include <hip/hip_bf16.h>
#include <math.h>

typedef __attribute__((ext_vector_type(8))) short short8;
typedef __attribute__((ext_vector_type(8))) unsigned short ushort8;
typedef __attribute__((ext_vector_type(4))) float f32x4;

// ---------------------------------------------------------------------------
// JAX threefry2x32 (20 rounds) — verified bit-exact vs jax.random in R1.
// ---------------------------------------------------------------------------
__host__ __device__ inline void threefry2x32(unsigned k0, unsigned k1,
                                             unsigned x0, unsigned x1,
                                             unsigned* out0, unsigned* out1) {
  unsigned ks0 = k0, ks1 = k1, ks2 = k0 ^ k1 ^ 0x1BD11BDAu;
  x0 += ks0; x1 += ks1;
#define TF_ROUND(r) { x0 += x1; x1 = (x1 << (r)) | (x1 >> (32 - (r))); x1 ^= x0; }
  TF_ROUND(13) TF_ROUND(15) TF_ROUND(26) TF_ROUND(6)
  x0 += ks1; x1 += ks2 + 1u;
  TF_ROUND(17) TF_ROUND(29) TF_ROUND(16) TF_ROUND(24)
  x0 += ks2; x1 += ks0 + 2u;
  TF_ROUND(13) TF_ROUND(15) TF_ROUND(26) TF_ROUND(6)
  x0 += ks0; x1 += ks1 + 3u;
  TF_ROUND(17) TF_ROUND(29) TF_ROUND(16) TF_ROUND(24)
  x0 += ks1; x1 += ks2 + 4u;
  TF_ROUND(13) TF_ROUND(15) TF_ROUND(26) TF_ROUND(6)
  x0 += ks2; x1 += ks0 + 5u;
#undef TF_ROUND
  *out0 = x0; *out1 = x1;
}

__device__ inline float jax_uniform01(unsigned key0, unsigned key1, unsigned i) {
  unsigned o0, o1;
  threefry2x32(key0, key1, 0u, i, &o0, &o1);
  unsigned bits = o0 ^ o1;
  return __uint_as_float((bits >> 9) | 0x3f800000u) - 1.0f;
}

__device__ inline unsigned short f2bf(float f) {
  unsigned u = __float_as_uint(f);
  u += 0x7fffu + ((u >> 16) & 1u);   // round-to-nearest-even
  return (unsigned short)(u >> 16);
}

__device__ inline float bf2f(unsigned short b) {
  return __uint_as_float(((unsigned)b) << 16);
}

// ---------------------------------------------------------------------------
// Graph prep kernels
// ---------------------------------------------------------------------------
__global__ void k_zero(int* p, int n) {
  int i = blockIdx.x * blockDim.x + threadIdx.x;
  if (i < n) p[i] = 0;
}

__global__ void k_deg(const int* __restrict__ ei, int E, int* __restrict__ deg) {
  int e = blockIdx.x * blockDim.x + threadIdx.x;
  if (e >= E) return;
  atomicAdd(&deg[ei[E + e]], 1);
}

// scan + cur/dinv init fused (single block)
__global__ void k_scan_prep(const int* __restrict__ deg, int* __restrict__ off,
                            int* __restrict__ cur, float* __restrict__ dinv, int n) {
  __shared__ int sums[1024];
  int t = threadIdx.x;
  int per = (n + 1023) >> 10;
  int base = t * per;
  int s = 0;
  for (int j = 0; j < per; ++j) { int idx = base + j; if (idx < n) s += deg[idx]; }
  sums[t] = s;
  __syncthreads();
  for (int d = 1; d < 1024; d <<= 1) {
    int v = (t >= d) ? sums[t - d] : 0;
    __syncthreads();
    sums[t] += v;
    __syncthreads();
  }
  int prefix = (t == 0) ? 0 : sums[t - 1];
  for (int j = 0; j < per; ++j) {
    int idx = base + j;
    if (idx < n) {
      off[idx] = prefix;
      cur[idx] = prefix;
      dinv[idx] = 1.0f / sqrtf((float)(deg[idx] + 1));
      prefix += deg[idx];
    }
  }
  if (t == 1023) off[n] = sums[1023];
}

__global__ void k_fill(const int* __restrict__ ei, int E,
                       int* __restrict__ cur, int* __restrict__ srcs) {
  int e = blockIdx.x * blockDim.x + threadIdx.x;
  if (e >= E) return;
  int s = ei[e];
  int d = ei[E + e];
  int pos = atomicAdd(&cur[d], 1);
  srcs[pos] = s;
}

// both weight transposes in one launch: W[K,N] fp32 -> WT[N,K] bf16
__global__ void k_cvt_all(const float* __restrict__ W1, unsigned short* __restrict__ W1T,
                          const float* __restrict__ W2, unsigned short* __restrict__ W2T) {
  const int S1 = 512 * 256, S2 = 256 * 128;
  int idx = blockIdx.x * blockDim.x + threadIdx.x;
  if (idx < S1) {
    int k = idx / 256, n = idx % 256;
    W1T[(size_t)n * 512 + k] = f2bf(W1[idx]);
  } else if (idx < S1 + S2) {
    int i2 = idx - S1;
    int k = i2 / 128, n = i2 % 128;
    W2T[(size_t)n * 256 + k] = f2bf(W2[i2]);
  }
}

// ---------------------------------------------------------------------------
// bf16 MFMA GEMM: C[M,N] = A[M,K] @ B[K,N], B given transposed bf16 [N,K].
// BM=64, BN=32*NF, BK=32; 4 waves (2x2), each 32 x (BN/2).
// ---------------------------------------------------------------------------
template <int NF, bool AF32, bool OBF>
__global__ __launch_bounds__(256) void k_gemm_mfma(const void* __restrict__ Ap,
                                                   const unsigned short* __restrict__ BT,
                                                   void* __restrict__ Cp,
                                                   int M, int N, int K) {
  constexpr int BN = 32 * NF;
  __shared__ unsigned short As[64][40];   // 80B rows: exact 2-way (free) on b128 reads
  __shared__ unsigned short Bs[BN][40];
  const int tid = threadIdx.x;
  const int row0 = blockIdx.y * 64;
  const int col0 = blockIdx.x * BN;
  const int w = tid >> 6, lane = tid & 63;
  const int wm = w >> 1, wn = w & 1;
  const int lr = lane & 15, lk = lane >> 4;

  f32x4 acc[2][NF];
#pragma unroll
  for (int mi = 0; mi < 2; ++mi)
#pragma unroll
    for (int ni = 0; ni < NF; ++ni) acc[mi][ni] = (f32x4)0.0f;

  const int ar = tid >> 2;            // A row 0..63
  const int aseg = (tid & 3) * 8;     // k offset within BK

  for (int k0 = 0; k0 < K; k0 += 32) {
    // ---- stage A (64 x 32 bf16) ----
    {
      int grow = row0 + ar;
      ushort8 av = (ushort8)0;
      if (grow < M) {
        if (AF32) {
          const float* A = (const float*)Ap;
          const float* p = &A[(size_t)grow * K + k0 + aseg];
          float4 v0 = *(const float4*)p;
          float4 v1 = *(const float4*)(p + 4);
          av[0] = f2bf(v0.x); av[1] = f2bf(v0.y); av[2] = f2bf(v0.z); av[3] = f2bf(v0.w);
          av[4] = f2bf(v1.x); av[5] = f2bf(v1.y); av[6] = f2bf(v1.z); av[7] = f2bf(v1.w);
        } else {
          const unsigned short* A = (const unsigned short*)Ap;
          av = *(const ushort8*)&A[(size_t)grow * K + k0 + aseg];
        }
      }
      *(ushort8*)&As[ar][aseg] = av;
    }
    // ---- stage B (BN rows of BT x 32) ----
#pragma unroll
    for (int p = 0; p < BN / 64; ++p) {
      int u = tid + p * 256;
      int br = u >> 2;
      int bseg = (u & 3) * 8;
      ushort8 bv = *(const ushort8*)&BT[(size_t)(col0 + br) * K + k0 + bseg];
      *(ushort8*)&Bs[br][bseg] = bv;
    }
    __syncthreads();

    short8 a[2], b[NF];
#pragma unroll
    for (int mi = 0; mi < 2; ++mi)
      a[mi] = *(const short8*)&As[wm * 32 + mi * 16 + lr][lk * 8];
#pragma unroll
    for (int ni = 0; ni < NF; ++ni)
      b[ni] = *(const short8*)&Bs[wn * (BN / 2) + ni * 16 + lr][lk * 8];
#pragma unroll
    for (int mi = 0; mi < 2; ++mi)
#pragma unroll
      for (int ni = 0; ni < NF; ++ni)
        acc[mi][ni] = __builtin_amdgcn_mfma_f32_16x16x32_bf16(a[mi], b[ni], acc[mi][ni], 0, 0, 0);
    __syncthreads();
  }

  // epilogue: C/D layout col=lane&15, row=(lane>>4)*4+reg  [m89-verified]
#pragma unroll
  for (int mi = 0; mi < 2; ++mi) {
    int rbase = row0 + wm * 32 + mi * 16 + lk * 4;
#pragma unroll
    for (int j = 0; j < 4; ++j) {
      int row = rbase + j;
      if (row < M) {
#pragma unroll
        for (int ni = 0; ni < NF; ++ni) {
          int col = col0 + wn * (BN / 2) + ni * 16 + lr;
          if (OBF) {
            ((unsigned short*)Cp)[(size_t)row * N + col] = f2bf(acc[mi][ni][j]);
          } else {
            ((float*)Cp)[(size_t)row * N + col] = acc[mi][ni][j];
          }
        }
      }
    }
  }
}

// ---------------------------------------------------------------------------
// fp32 tiled GEMM (layer 3 only, N=10)
// ---------------------------------------------------------------------------
__global__ __launch_bounds__(256) void k_gemm(const float* __restrict__ A,
                                              const float* __restrict__ B,
                                              float* __restrict__ C,
                                              int M, int N, int K) {
  __shared__ float As[64][17];
  __shared__ float Bs[16][64];
  const int tid = threadIdx.x;
  const int tx = tid & 15, ty = tid >> 4;
  const int row0 = blockIdx.y * 64, col0 = blockIdx.x * 64;
  const int am = tid >> 2;
  const int aq = (tid & 3) * 4;
  const int bk = tid >> 4;
  const int bg = (tid & 15) * 4;
  const bool nvec = ((N & 3) == 0);
  float acc[4][4] = {{0.f}};

  for (int k0 = 0; k0 < K; k0 += 16) {
    {
      int row = row0 + am;
      if (row < M) {
        const float4 v = *reinterpret_cast<const float4*>(&A[(size_t)row * K + k0 + aq]);
        As[am][aq + 0] = v.x; As[am][aq + 1] = v.y;
        As[am][aq + 2] = v.z; As[am][aq + 3] = v.w;
      } else {
        As[am][aq + 0] = 0.f; As[am][aq + 1] = 0.f;
        As[am][aq + 2] = 0.f; As[am][aq + 3] = 0.f;
      }
    }
    {
      int krow = k0 + bk;
      if (nvec && (col0 + bg + 4 <= N)) {
        const float4 v = *reinterpret_cast<const float4*>(&B[(size_t)krow * N + col0 + bg]);
        Bs[bk][bg + 0] = v.x; Bs[bk][bg + 1] = v.y;
        Bs[bk][bg + 2] = v.z; Bs[bk][bg + 3] = v.w;
      } else {
        for (int j = 0; j < 4; ++j) {
          int col = col0 + bg + j;
          Bs[bk][bg + j] = (col < N) ? B[(size_t)krow * N + col] : 0.f;
        }
      }
    }
    __syncthreads();
#pragma unroll
    for (int kk = 0; kk < 16; ++kk) {
      float a0 = As[ty * 4 + 0][kk];
      float a1 = As[ty * 4 + 1][kk];
      float a2 = As[ty * 4 + 2][kk];
      float a3 = As[ty * 4 + 3][kk];
      float4 bv = *reinterpret_cast<const float4*>(&Bs[kk][tx * 4]);
      acc[0][0] += a0 * bv.x; acc[0][1] += a0 * bv.y; acc[0][2] += a0 * bv.z; acc[0][3] += a0 * bv.w;
      acc[1][0] += a1 * bv.x; acc[1][1] += a1 * bv.y; acc[1][2] += a1 * bv.z; acc[1][3] += a1 * bv.w;
      acc[2][0] += a2 * bv.x; acc[2][1] += a2 * bv.y; acc[2][2] += a2 * bv.z; acc[2][3] += a2 * bv.w;
      acc[3][0] += a3 * bv.x; acc[3][1] += a3 * bv.y; acc[3][2] += a3 * bv.z; acc[3][3] += a3 * bv.w;
    }
    __syncthreads();
  }

  for (int i = 0; i < 4; ++i) {
    int row = row0 + ty * 4 + i;
    if (row >= M) continue;
    for (int j = 0; j < 4; ++j) {
      int col = col0 + tx * 4 + j;
      if (col < N) C[(size_t)row * N + col] = acc[i][j];
    }
  }
}

// ---------------------------------------------------------------------------
// Wave-per-node GCN aggregation over bf16 h (+bias, relu, jax dropout).
// C bf16 elems per lane (F = 64*C); 4 nodes per 256-thread block; unroll x4.
// ---------------------------------------------------------------------------
template <int C, bool OBF>
__global__ __launch_bounds__(256) void k_agg_bf(const unsigned short* __restrict__ h,
                                                void* __restrict__ outv,
                                                const int* __restrict__ off,
                                                const int* __restrict__ srcs,
                                                const float* __restrict__ dinv,
                                                const float* __restrict__ bias,
                                                unsigned key0, unsigned key1, int n) {
  typedef __attribute__((ext_vector_type(C))) unsigned short ushortC;
  const int node = blockIdx.x * (blockDim.x >> 6) + (threadIdx.x >> 6);
  if (node >= n) return;
  const int lane = threadIdx.x & 63;
  const int F = 64 * C;
  const float dv = dinv[node];

  float acc[C];
  {
    ushortC r = *(const ushortC*)(h + (size_t)node * F + lane * C);
    float wv = dv * dv;
#pragma unroll
    for (int j = 0; j < C; ++j) acc[j] = bf2f(r[j]) * wv;
  }
  int e = off[node];
  const int e1 = off[node + 1];
  for (; e + 4 <= e1; e += 4) {
    int s0 = srcs[e + 0], s1 = srcs[e + 1], s2 = srcs[e + 2], s3 = srcs[e + 3];
    float w0 = dinv[s0] * dv, w1 = dinv[s1] * dv, w2 = dinv[s2] * dv, w3 = dinv[s3] * dv;
    ushortC r0 = *(const ushortC*)(h + (size_t)s0 * F + lane * C);
    ushortC r1 = *(const ushortC*)(h + (size_t)s1 * F + lane * C);
    ushortC r2 = *(const ushortC*)(h + (size_t)s2 * F + lane * C);
    ushortC r3 = *(const ushortC*)(h + (size_t)s3 * F + lane * C);
#pragma unroll
    for (int j = 0; j < C; ++j)
      acc[j] += bf2f(r0[j]) * w0 + bf2f(r1[j]) * w1 + bf2f(r2[j]) * w2 + bf2f(r3[j]) * w3;
  }
  for (; e < e1; ++e) {
    int s = srcs[e];
    float wv = dinv[s] * dv;
    ushortC r = *(const ushortC*)(h + (size_t)s * F + lane * C);
#pragma unroll
    for (int j = 0; j < C; ++j) acc[j] += bf2f(r[j]) * wv;
  }
#pragma unroll
  for (int j = 0; j < C; ++j) {
    float v = acc[j] + bias[lane * C + j];
    v = fmaxf(v, 0.0f);
    unsigned i = (unsigned)(node * F + lane * C + j);
    float u = jax_uniform01(key0, key1, i);
    v = (u < 0.8f) ? (v * 1.25f) : 0.0f;
    acc[j] = v;
  }
  if (OBF) {
    unsigned short* op = (unsigned short*)outv + (size_t)node * F + lane * C;
#pragma unroll
    for (int j = 0; j < C; ++j) op[j] = f2bf(acc[j]);
  } else {
    float* op = (float*)outv + (size_t)node * F + lane * C;
#pragma unroll
    for (int j = 0; j < C; ++j) op[j] = acc[j];
  }
}

// ---------------------------------------------------------------------------
// layer 3: wave-per-node aggregate (10-dim) + bias + log_softmax.
// lanes 0..9 own features; gathers coalesced 40B; edge loop unrolled x4;
// shuffle-reduce for max/sum.
// ---------------------------------------------------------------------------
__global__ __launch_bounds__(256) void k_agg3_lsm_v2(const float* __restrict__ h,
                                                     float* __restrict__ out,
                                                     const int* __restrict__ off,
                                                     const int* __restrict__ srcs,
                                                     const float* __restrict__ dinv,
                                                     const float* __restrict__ b,
                                                     int n) {
  const int node = blockIdx.x * 4 + (threadIdx.x >> 6);
  if (node >= n) return;
  const int lane = threadIdx.x & 63;
  const bool act = (lane < 10);
  const float dv = dinv[node];

  float acc = 0.0f;
  if (act) acc = h[(size_t)node * 10 + lane] * dv * dv;
  int e = off[node];
  const int e1 = off[node + 1];
  for (; e + 4 <= e1; e += 4) {
    int s0 = srcs[e + 0], s1 = srcs[e + 1], s2 = srcs[e + 2], s3 = srcs[e + 3];
    float w0 = dinv[s0] * dv, w1 = dinv[s1] * dv, w2 = dinv[s2] * dv, w3 = dinv[s3] * dv;
    if (act) {
      acc += h[(size_t)s0 * 10 + lane] * w0 + h[(size_t)s1 * 10 + lane] * w1 +
             h[(size_t)s2 * 10 + lane] * w2 + h[(size_t)s3 * 10 + lane] * w3;
    }
  }
  for (; e < e1; ++e) {
    int s = srcs[e];
    float w = dinv[s] * dv;
    if (act) acc += h[(size_t)s * 10 + lane] * w;
  }
  float v = act ? (acc + b[lane]) : -1e30f;
  float m = v;
#pragma unroll
  for (int o = 32; o; o >>= 1) m = fmaxf(m, __shfl_xor(m, o));
  float p = act ? expf(v - m) : 0.0f;
  float ssum = p;
#pragma unroll
  for (int o = 32; o; o >>= 1) ssum += __shfl_xor(ssum, o);
  float lse = m + logf(ssum);
  if (act) out[(size_t)node * 10 + lane] = v - lse;
}

// ---------------------------------------------------------------------------
extern "C" void kernel_launch(void* const* d_in, const int* in_sizes, int n_in,
                              void* d_out, int out_size, void* d_ws, size_t ws_size,
                              hipStream_t stream) {
  const float* x  = (const float*)d_in[0];
  const int*   ei = (const int*)d_in[1];
  const float* W1 = (const float*)d_in[2];
  const float* b1 = (const float*)d_in[3];
  const float* W2 = (const float*)d_in[4];
  const float* b2 = (const float*)d_in[5];
  const float* W3 = (const float*)d_in[6];
  const float* b3 = (const float*)d_in[7];
  float* out = (float*)d_out;

  const int N = 20000;
  const int E = in_sizes[1] / 2;
  const int D1 = 256, D2 = 128;

  char* ws = (char*)d_ws;
  auto carve = [&](size_t bytes) -> char* {
    char* p = ws;
    ws += (bytes + 255) & ~(size_t)255;
    return p;
  };
  int*   deg  = (int*)carve((size_t)N * 4);
  int*   off  = (int*)carve((size_t)(N + 1) * 4);
  int*   cur  = (int*)carve((size_t)N * 4);
  float* dinv = (float*)carve((size_t)N * 4);
  int*   srcs = (int*)carve((size_t)E * 4);
  unsigned short* W1T = (unsigned short*)carve((size_t)D1 * 512 * 2);
  unsigned short* W2T = (unsigned short*)carve((size_t)D2 * D1 * 2);
  unsigned short* bufHb = (unsigned short*)carve((size_t)N * D1 * 2);   // h1(bf16), then h2(bf16)
  unsigned short* bufA_bf = (unsigned short*)carve((size_t)N * D1 * 2); // agg1 bf16; agg2 fp32 reuse
  float* bufA2 = (float*)bufA_bf;
  float* bufH3 = (float*)carve((size_t)N * 10 * 4);                     // h3 fp32

  unsigned dk1_0, dk1_1, dk2_0, dk2_1;
  threefry2x32(0u, 1u, 0u, 0u, &dk1_0, &dk1_1);
  threefry2x32(0u, 1u, 0u, 1u, &dk2_0, &dk2_1);

  // graph prep + weight conversion (11 dispatches total this launch)
  k_zero<<<(N + 255) / 256, 256, 0, stream>>>(deg, N);
  k_deg<<<(E + 255) / 256, 256, 0, stream>>>(ei, E, deg);
  k_scan_prep<<<1, 1024, 0, stream>>>(deg, off, cur, dinv, N);
  k_fill<<<(E + 255) / 256, 256, 0, stream>>>(ei, E, cur, srcs);
  k_cvt_all<<<(512 * 256 + 256 * 128 + 255) / 256, 256, 0, stream>>>(W1, W1T, W2, W2T);

  // layer 1: h1(bf16) = x @ W1 (BN=256, single column block -> x read once)
  k_gemm_mfma<8, true, true><<<dim3(1, (N + 63) / 64), 256, 0, stream>>>(x, W1T, bufHb, N, D1, 512);
  k_agg_bf<4, true><<<(N + 3) / 4, 256, 0, stream>>>(bufHb, bufA_bf, off, srcs, dinv, b1, dk1_0, dk1_1, N);

  // layer 2: h2(bf16) = a1 @ W2
  k_gemm_mfma<4, false, true><<<dim3(1, (N + 63) / 64), 256, 0, stream>>>(bufA_bf, W2T, bufHb, N, D2, D1);
  k_agg_bf<2, false><<<(N + 3) / 4, 256, 0, stream>>>(bufHb, bufA2, off, srcs, dinv, b2, dk2_0, dk2_1, N);

  // layer 3 (fp32, N=10) + wave-parallel agg + log_softmax
  k_gemm<<<dim3(1, (N + 63) / 64), 256, 0, stream>>>(bufA2, W3, bufH3, N, 10, D2);
  k_agg3_lsm_v2<<<(N + 3) / 4, 256, 0, stream>>>(bufH3, out, off, srcs, dinv, b3, N);
}

// Round 5
// 162.038 us; speedup vs baseline: 1.2607x; 1.2607x over previous
//
#include <hip/hip_runtime.h>
#include <hip/hip_bf16.h>
#include <math.h>

typedef __attribute__((ext_vector_type(8))) short short8;
typedef __attribute__((ext_vector_type(8))) unsigned short ushort8;
typedef __attribute__((ext_vector_type(4))) float f32x4;

// ---------------------------------------------------------------------------
// JAX threefry2x32 (20 rounds) — verified bit-exact vs jax.random in R1.
// ---------------------------------------------------------------------------
__host__ __device__ inline void threefry2x32(unsigned k0, unsigned k1,
                                             unsigned x0, unsigned x1,
                                             unsigned* out0, unsigned* out1) {
  unsigned ks0 = k0, ks1 = k1, ks2 = k0 ^ k1 ^ 0x1BD11BDAu;
  x0 += ks0; x1 += ks1;
#define TF_ROUND(r) { x0 += x1; x1 = (x1 << (r)) | (x1 >> (32 - (r))); x1 ^= x0; }
  TF_ROUND(13) TF_ROUND(15) TF_ROUND(26) TF_ROUND(6)
  x0 += ks1; x1 += ks2 + 1u;
  TF_ROUND(17) TF_ROUND(29) TF_ROUND(16) TF_ROUND(24)
  x0 += ks2; x1 += ks0 + 2u;
  TF_ROUND(13) TF_ROUND(15) TF_ROUND(26) TF_ROUND(6)
  x0 += ks0; x1 += ks1 + 3u;
  TF_ROUND(17) TF_ROUND(29) TF_ROUND(16) TF_ROUND(24)
  x0 += ks1; x1 += ks2 + 4u;
  TF_ROUND(13) TF_ROUND(15) TF_ROUND(26) TF_ROUND(6)
  x0 += ks2; x1 += ks0 + 5u;
#undef TF_ROUND
  *out0 = x0; *out1 = x1;
}

__device__ inline float jax_uniform01(unsigned key0, unsigned key1, unsigned i) {
  unsigned o0, o1;
  threefry2x32(key0, key1, 0u, i, &o0, &o1);
  unsigned bits = o0 ^ o1;
  return __uint_as_float((bits >> 9) | 0x3f800000u) - 1.0f;
}

__device__ inline unsigned short f2bf(float f) {
  unsigned u = __float_as_uint(f);
  u += 0x7fffu + ((u >> 16) & 1u);   // round-to-nearest-even
  return (unsigned short)(u >> 16);
}

__device__ inline float bf2f(unsigned short b) {
  return __uint_as_float(((unsigned)b) << 16);
}

// ---------------------------------------------------------------------------
// Graph prep kernels
// ---------------------------------------------------------------------------
__global__ void k_zero(int* p, int n) {
  int i = blockIdx.x * blockDim.x + threadIdx.x;
  if (i < n) p[i] = 0;
}

__global__ void k_deg(const int* __restrict__ ei, int E, int* __restrict__ deg) {
  int e = blockIdx.x * blockDim.x + threadIdx.x;
  if (e >= E) return;
  atomicAdd(&deg[ei[E + e]], 1);
}

// ---- parallel 3-phase exclusive scan of deg -> off/cur, plus dinv ----
// Phase A: per-256-block sums
__global__ __launch_bounds__(256) void k_bsum(const int* __restrict__ deg,
                                              int* __restrict__ bsum, int n) {
  int i = blockIdx.x * 256 + threadIdx.x;
  int v = (i < n) ? deg[i] : 0;
#pragma unroll
  for (int o = 32; o; o >>= 1) v += __shfl_down(v, o);
  __shared__ int ws[4];
  if ((threadIdx.x & 63) == 0) ws[threadIdx.x >> 6] = v;
  __syncthreads();
  if (threadIdx.x == 0) bsum[blockIdx.x] = ws[0] + ws[1] + ws[2] + ws[3];
}

// Phase B: exclusive scan of block sums (nb <= 128), single tiny block
__global__ void k_bscan(int* __restrict__ bsum, int nb) {
  __shared__ int s[128];
  int t = threadIdx.x;
  int v = (t < nb) ? bsum[t] : 0;
  s[t] = v;
  __syncthreads();
  for (int d = 1; d < 128; d <<= 1) {
    int u = (t >= d) ? s[t - d] : 0;
    __syncthreads();
    s[t] += u;
    __syncthreads();
  }
  if (t < nb) bsum[t] = (t == 0) ? 0 : s[t - 1];
}

// Phase C: intra-block scan + block base -> off/cur/dinv (coalesced)
__global__ __launch_bounds__(256) void k_scatter(const int* __restrict__ deg,
                                                 const int* __restrict__ bsum,
                                                 int* __restrict__ off, int* __restrict__ cur,
                                                 float* __restrict__ dinv, int n) {
  int i = blockIdx.x * 256 + threadIdx.x;
  int d = (i < n) ? deg[i] : 0;
  int lane = threadIdx.x & 63, w = threadIdx.x >> 6;
  int inc = d;
#pragma unroll
  for (int o = 1; o < 64; o <<= 1) {
    int u = __shfl_up(inc, o);
    if (lane >= o) inc += u;
  }
  __shared__ int wsum[4];
  if (lane == 63) wsum[w] = inc;
  __syncthreads();
  int wbase = 0;
  for (int k = 0; k < w; ++k) wbase += wsum[k];
  int excl = inc - d + wbase + bsum[blockIdx.x];
  if (i < n) {
    off[i] = excl;
    cur[i] = excl;
    dinv[i] = 1.0f / sqrtf((float)(d + 1));
    if (i == n - 1) off[n] = excl + d;
  }
}

__global__ void k_fill(const int* __restrict__ ei, int E,
                       int* __restrict__ cur, int* __restrict__ srcs) {
  int e = blockIdx.x * blockDim.x + threadIdx.x;
  if (e >= E) return;
  int s = ei[e];
  int d = ei[E + e];
  int pos = atomicAdd(&cur[d], 1);
  srcs[pos] = s;
}

// both weight transposes in one launch: W[K,N] fp32 -> WT[N,K] bf16
__global__ void k_cvt_all(const float* __restrict__ W1, unsigned short* __restrict__ W1T,
                          const float* __restrict__ W2, unsigned short* __restrict__ W2T) {
  const int S1 = 512 * 256, S2 = 256 * 128;
  int idx = blockIdx.x * blockDim.x + threadIdx.x;
  if (idx < S1) {
    int k = idx / 256, n = idx % 256;
    W1T[(size_t)n * 512 + k] = f2bf(W1[idx]);
  } else if (idx < S1 + S2) {
    int i2 = idx - S1;
    int k = i2 / 128, n = i2 % 128;
    W2T[(size_t)n * 256 + k] = f2bf(W2[i2]);
  }
}

// ---------------------------------------------------------------------------
// bf16 MFMA GEMM: C[M,N] = A[M,K] @ B[K,N], B given transposed bf16 [N,K].
// BM=64, BN=32*NF, BK=32; 4 waves (2x2), each 32 x (BN/2).
// ---------------------------------------------------------------------------
template <int NF, bool AF32, bool OBF>
__global__ __launch_bounds__(256) void k_gemm_mfma(const void* __restrict__ Ap,
                                                   const unsigned short* __restrict__ BT,
                                                   void* __restrict__ Cp,
                                                   int M, int N, int K) {
  constexpr int BN = 32 * NF;
  __shared__ unsigned short As[64][40];   // 80B rows: exact 2-way (free) on b128 reads
  __shared__ unsigned short Bs[BN][40];
  const int tid = threadIdx.x;
  const int row0 = blockIdx.y * 64;
  const int col0 = blockIdx.x * BN;
  const int w = tid >> 6, lane = tid & 63;
  const int wm = w >> 1, wn = w & 1;
  const int lr = lane & 15, lk = lane >> 4;

  f32x4 acc[2][NF];
#pragma unroll
  for (int mi = 0; mi < 2; ++mi)
#pragma unroll
    for (int ni = 0; ni < NF; ++ni) acc[mi][ni] = (f32x4)0.0f;

  const int ar = tid >> 2;            // A row 0..63
  const int aseg = (tid & 3) * 8;     // k offset within BK

  for (int k0 = 0; k0 < K; k0 += 32) {
    // ---- stage A (64 x 32 bf16) ----
    {
      int grow = row0 + ar;
      ushort8 av = (ushort8)0;
      if (grow < M) {
        if (AF32) {
          const float* A = (const float*)Ap;
          const float* p = &A[(size_t)grow * K + k0 + aseg];
          float4 v0 = *(const float4*)p;
          float4 v1 = *(const float4*)(p + 4);
          av[0] = f2bf(v0.x); av[1] = f2bf(v0.y); av[2] = f2bf(v0.z); av[3] = f2bf(v0.w);
          av[4] = f2bf(v1.x); av[5] = f2bf(v1.y); av[6] = f2bf(v1.z); av[7] = f2bf(v1.w);
        } else {
          const unsigned short* A = (const unsigned short*)Ap;
          av = *(const ushort8*)&A[(size_t)grow * K + k0 + aseg];
        }
      }
      *(ushort8*)&As[ar][aseg] = av;
    }
    // ---- stage B (BN rows of BT x 32) ----
#pragma unroll
    for (int p = 0; p < BN / 64; ++p) {
      int u = tid + p * 256;
      int br = u >> 2;
      int bseg = (u & 3) * 8;
      ushort8 bv = *(const ushort8*)&BT[(size_t)(col0 + br) * K + k0 + bseg];
      *(ushort8*)&Bs[br][bseg] = bv;
    }
    __syncthreads();

    short8 a[2], b[NF];
#pragma unroll
    for (int mi = 0; mi < 2; ++mi)
      a[mi] = *(const short8*)&As[wm * 32 + mi * 16 + lr][lk * 8];
#pragma unroll
    for (int ni = 0; ni < NF; ++ni)
      b[ni] = *(const short8*)&Bs[wn * (BN / 2) + ni * 16 + lr][lk * 8];
#pragma unroll
    for (int mi = 0; mi < 2; ++mi)
#pragma unroll
      for (int ni = 0; ni < NF; ++ni)
        acc[mi][ni] = __builtin_amdgcn_mfma_f32_16x16x32_bf16(a[mi], b[ni], acc[mi][ni], 0, 0, 0);
    __syncthreads();
  }

  // epilogue: C/D layout col=lane&15, row=(lane>>4)*4+reg  [m89-verified]
#pragma unroll
  for (int mi = 0; mi < 2; ++mi) {
    int rbase = row0 + wm * 32 + mi * 16 + lk * 4;
#pragma unroll
    for (int j = 0; j < 4; ++j) {
      int row = rbase + j;
      if (row < M) {
#pragma unroll
        for (int ni = 0; ni < NF; ++ni) {
          int col = col0 + wn * (BN / 2) + ni * 16 + lr;
          if (OBF) {
            ((unsigned short*)Cp)[(size_t)row * N + col] = f2bf(acc[mi][ni][j]);
          } else {
            ((float*)Cp)[(size_t)row * N + col] = acc[mi][ni][j];
          }
        }
      }
    }
  }
}

// ---------------------------------------------------------------------------
// fp32 tiled GEMM (layer 3 only, N=10)
// ---------------------------------------------------------------------------
__global__ __launch_bounds__(256) void k_gemm(const float* __restrict__ A,
                                              const float* __restrict__ B,
                                              float* __restrict__ C,
                                              int M, int N, int K) {
  __shared__ float As[64][17];
  __shared__ float Bs[16][64];
  const int tid = threadIdx.x;
  const int tx = tid & 15, ty = tid >> 4;
  const int row0 = blockIdx.y * 64, col0 = blockIdx.x * 64;
  const int am = tid >> 2;
  const int aq = (tid & 3) * 4;
  const int bk = tid >> 4;
  const int bg = (tid & 15) * 4;
  const bool nvec = ((N & 3) == 0);
  float acc[4][4] = {{0.f}};

  for (int k0 = 0; k0 < K; k0 += 16) {
    {
      int row = row0 + am;
      if (row < M) {
        const float4 v = *reinterpret_cast<const float4*>(&A[(size_t)row * K + k0 + aq]);
        As[am][aq + 0] = v.x; As[am][aq + 1] = v.y;
        As[am][aq + 2] = v.z; As[am][aq + 3] = v.w;
      } else {
        As[am][aq + 0] = 0.f; As[am][aq + 1] = 0.f;
        As[am][aq + 2] = 0.f; As[am][aq + 3] = 0.f;
      }
    }
    {
      int krow = k0 + bk;
      if (nvec && (col0 + bg + 4 <= N)) {
        const float4 v = *reinterpret_cast<const float4*>(&B[(size_t)krow * N + col0 + bg]);
        Bs[bk][bg + 0] = v.x; Bs[bk][bg + 1] = v.y;
        Bs[bk][bg + 2] = v.z; Bs[bk][bg + 3] = v.w;
      } else {
        for (int j = 0; j < 4; ++j) {
          int col = col0 + bg + j;
          Bs[bk][bg + j] = (col < N) ? B[(size_t)krow * N + col] : 0.f;
        }
      }
    }
    __syncthreads();
#pragma unroll
    for (int kk = 0; kk < 16; ++kk) {
      float a0 = As[ty * 4 + 0][kk];
      float a1 = As[ty * 4 + 1][kk];
      float a2 = As[ty * 4 + 2][kk];
      float a3 = As[ty * 4 + 3][kk];
      float4 bv = *reinterpret_cast<const float4*>(&Bs[kk][tx * 4]);
      acc[0][0] += a0 * bv.x; acc[0][1] += a0 * bv.y; acc[0][2] += a0 * bv.z; acc[0][3] += a0 * bv.w;
      acc[1][0] += a1 * bv.x; acc[1][1] += a1 * bv.y; acc[1][2] += a1 * bv.z; acc[1][3] += a1 * bv.w;
      acc[2][0] += a2 * bv.x; acc[2][1] += a2 * bv.y; acc[2][2] += a2 * bv.z; acc[2][3] += a2 * bv.w;
      acc[3][0] += a3 * bv.x; acc[3][1] += a3 * bv.y; acc[3][2] += a3 * bv.z; acc[3][3] += a3 * bv.w;
    }
    __syncthreads();
  }

  for (int i = 0; i < 4; ++i) {
    int row = row0 + ty * 4 + i;
    if (row >= M) continue;
    for (int j = 0; j < 4; ++j) {
      int col = col0 + tx * 4 + j;
      if (col < N) C[(size_t)row * N + col] = acc[i][j];
    }
  }
}

// ---------------------------------------------------------------------------
// Wave-per-node GCN aggregation over bf16 h (+bias, relu, jax dropout).
// C bf16 elems per lane (F = 64*C); 4 nodes per 256-thread block; unroll x4.
// ---------------------------------------------------------------------------
template <int C, bool OBF>
__global__ __launch_bounds__(256) void k_agg_bf(const unsigned short* __restrict__ h,
                                                void* __restrict__ outv,
                                                const int* __restrict__ off,
                                                const int* __restrict__ srcs,
                                                const float* __restrict__ dinv,
                                                const float* __restrict__ bias,
                                                unsigned key0, unsigned key1, int n) {
  typedef __attribute__((ext_vector_type(C))) unsigned short ushortC;
  const int node = blockIdx.x * (blockDim.x >> 6) + (threadIdx.x >> 6);
  if (node >= n) return;
  const int lane = threadIdx.x & 63;
  const int F = 64 * C;
  const float dv = dinv[node];

  float acc[C];
  {
    ushortC r = *(const ushortC*)(h + (size_t)node * F + lane * C);
    float wv = dv * dv;
#pragma unroll
    for (int j = 0; j < C; ++j) acc[j] = bf2f(r[j]) * wv;
  }
  int e = off[node];
  const int e1 = off[node + 1];
  for (; e + 4 <= e1; e += 4) {
    int s0 = srcs[e + 0], s1 = srcs[e + 1], s2 = srcs[e + 2], s3 = srcs[e + 3];
    float w0 = dinv[s0] * dv, w1 = dinv[s1] * dv, w2 = dinv[s2] * dv, w3 = dinv[s3] * dv;
    ushortC r0 = *(const ushortC*)(h + (size_t)s0 * F + lane * C);
    ushortC r1 = *(const ushortC*)(h + (size_t)s1 * F + lane * C);
    ushortC r2 = *(const ushortC*)(h + (size_t)s2 * F + lane * C);
    ushortC r3 = *(const ushortC*)(h + (size_t)s3 * F + lane * C);
#pragma unroll
    for (int j = 0; j < C; ++j)
      acc[j] += bf2f(r0[j]) * w0 + bf2f(r1[j]) * w1 + bf2f(r2[j]) * w2 + bf2f(r3[j]) * w3;
  }
  for (; e < e1; ++e) {
    int s = srcs[e];
    float wv = dinv[s] * dv;
    ushortC r = *(const ushortC*)(h + (size_t)s * F + lane * C);
#pragma unroll
    for (int j = 0; j < C; ++j) acc[j] += bf2f(r[j]) * wv;
  }
#pragma unroll
  for (int j = 0; j < C; ++j) {
    float v = acc[j] + bias[lane * C + j];
    v = fmaxf(v, 0.0f);
    unsigned i = (unsigned)(node * F + lane * C + j);
    float u = jax_uniform01(key0, key1, i);
    v = (u < 0.8f) ? (v * 1.25f) : 0.0f;
    acc[j] = v;
  }
  if (OBF) {
    unsigned short* op = (unsigned short*)outv + (size_t)node * F + lane * C;
#pragma unroll
    for (int j = 0; j < C; ++j) op[j] = f2bf(acc[j]);
  } else {
    float* op = (float*)outv + (size_t)node * F + lane * C;
#pragma unroll
    for (int j = 0; j < C; ++j) op[j] = acc[j];
  }
}

// ---------------------------------------------------------------------------
// layer 3: wave-per-node aggregate (10-dim) + bias + log_softmax.
// ---------------------------------------------------------------------------
__global__ __launch_bounds__(256) void k_agg3_lsm_v2(const float* __restrict__ h,
                                                     float* __restrict__ out,
                                                     const int* __restrict__ off,
                                                     const int* __restrict__ srcs,
                                                     const float* __restrict__ dinv,
                                                     const float* __restrict__ b,
                                                     int n) {
  const int node = blockIdx.x * 4 + (threadIdx.x >> 6);
  if (node >= n) return;
  const int lane = threadIdx.x & 63;
  const bool act = (lane < 10);
  const float dv = dinv[node];

  float acc = 0.0f;
  if (act) acc = h[(size_t)node * 10 + lane] * dv * dv;
  int e = off[node];
  const int e1 = off[node + 1];
  for (; e + 4 <= e1; e += 4) {
    int s0 = srcs[e + 0], s1 = srcs[e + 1], s2 = srcs[e + 2], s3 = srcs[e + 3];
    float w0 = dinv[s0] * dv, w1 = dinv[s1] * dv, w2 = dinv[s2] * dv, w3 = dinv[s3] * dv;
    if (act) {
      acc += h[(size_t)s0 * 10 + lane] * w0 + h[(size_t)s1 * 10 + lane] * w1 +
             h[(size_t)s2 * 10 + lane] * w2 + h[(size_t)s3 * 10 + lane] * w3;
    }
  }
  for (; e < e1; ++e) {
    int s = srcs[e];
    float w = dinv[s] * dv;
    if (act) acc += h[(size_t)s * 10 + lane] * w;
  }
  float v = act ? (acc + b[lane]) : -1e30f;
  float m = v;
#pragma unroll
  for (int o = 32; o; o >>= 1) m = fmaxf(m, __shfl_xor(m, o));
  float p = act ? expf(v - m) : 0.0f;
  float ssum = p;
#pragma unroll
  for (int o = 32; o; o >>= 1) ssum += __shfl_xor(ssum, o);
  float lse = m + logf(ssum);
  if (act) out[(size_t)node * 10 + lane] = v - lse;
}

// ---------------------------------------------------------------------------
extern "C" void kernel_launch(void* const* d_in, const int* in_sizes, int n_in,
                              void* d_out, int out_size, void* d_ws, size_t ws_size,
                              hipStream_t stream) {
  const float* x  = (const float*)d_in[0];
  const int*   ei = (const int*)d_in[1];
  const float* W1 = (const float*)d_in[2];
  const float* b1 = (const float*)d_in[3];
  const float* W2 = (const float*)d_in[4];
  const float* b2 = (const float*)d_in[5];
  const float* W3 = (const float*)d_in[6];
  const float* b3 = (const float*)d_in[7];
  float* out = (float*)d_out;

  const int N = 20000;
  const int E = in_sizes[1] / 2;
  const int D1 = 256, D2 = 128;
  const int NB = (N + 255) / 256;   // 79 scan blocks

  char* ws = (char*)d_ws;
  auto carve = [&](size_t bytes) -> char* {
    char* p = ws;
    ws += (bytes + 255) & ~(size_t)255;
    return p;
  };
  int*   deg  = (int*)carve((size_t)N * 4);
  int*   off  = (int*)carve((size_t)(N + 1) * 4);
  int*   cur  = (int*)carve((size_t)N * 4);
  float* dinv = (float*)carve((size_t)N * 4);
  int*   bsum = (int*)carve((size_t)128 * 4);
  int*   srcs = (int*)carve((size_t)E * 4);
  unsigned short* W1T = (unsigned short*)carve((size_t)D1 * 512 * 2);
  unsigned short* W2T = (unsigned short*)carve((size_t)D2 * D1 * 2);
  unsigned short* bufHb = (unsigned short*)carve((size_t)N * D1 * 2);   // h1(bf16), then h2(bf16)
  unsigned short* bufA_bf = (unsigned short*)carve((size_t)N * D1 * 2); // agg1 bf16; agg2 fp32 reuse
  float* bufA2 = (float*)bufA_bf;
  float* bufH3 = (float*)carve((size_t)N * 10 * 4);                     // h3 fp32

  unsigned dk1_0, dk1_1, dk2_0, dk2_1;
  threefry2x32(0u, 1u, 0u, 0u, &dk1_0, &dk1_1);
  threefry2x32(0u, 1u, 0u, 1u, &dk2_0, &dk2_1);

  // graph prep (parallel scan) + weight conversion
  k_zero<<<(N + 255) / 256, 256, 0, stream>>>(deg, N);
  k_deg<<<(E + 255) / 256, 256, 0, stream>>>(ei, E, deg);
  k_bsum<<<NB, 256, 0, stream>>>(deg, bsum, N);
  k_bscan<<<1, 128, 0, stream>>>(bsum, NB);
  k_scatter<<<NB, 256, 0, stream>>>(deg, bsum, off, cur, dinv, N);
  k_fill<<<(E + 255) / 256, 256, 0, stream>>>(ei, E, cur, srcs);
  k_cvt_all<<<(512 * 256 + 256 * 128 + 255) / 256, 256, 0, stream>>>(W1, W1T, W2, W2T);

  // layer 1: h1(bf16) = x @ W1 (BN=128, 626 blocks for load balance)
  k_gemm_mfma<4, true, true><<<dim3(D1 / 128, (N + 63) / 64), 256, 0, stream>>>(x, W1T, bufHb, N, D1, 512);
  k_agg_bf<4, true><<<(N + 3) / 4, 256, 0, stream>>>(bufHb, bufA_bf, off, srcs, dinv, b1, dk1_0, dk1_1, N);

  // layer 2: h2(bf16) = a1 @ W2
  k_gemm_mfma<4, false, true><<<dim3(D2 / 128, (N + 63) / 64), 256, 0, stream>>>(bufA_bf, W2T, bufHb, N, D2, D1);
  k_agg_bf<2, false><<<(N + 3) / 4, 256, 0, stream>>>(bufHb, bufA2, off, srcs, dinv, b2, dk2_0, dk2_1, N);

  // layer 3 (fp32, N=10) + wave-parallel agg + log_softmax
  k_gemm<<<dim3(1, (N + 63) / 64), 256, 0, stream>>>(bufA2, W3, bufH3, N, 10, D2);
  k_agg3_lsm_v2<<<(N + 3) / 4, 256, 0, stream>>>(bufH3, out, off, srcs, dinv, b3, N);
}

// Round 6
// 160.230 us; speedup vs baseline: 1.2750x; 1.0113x over previous
//
#include <hip/hip_runtime.h>
#include <hip/hip_bf16.h>
#include <math.h>

typedef __attribute__((ext_vector_type(8))) short short8;
typedef __attribute__((ext_vector_type(8))) unsigned short ushort8;
typedef __attribute__((ext_vector_type(4))) float f32x4;

// ---------------------------------------------------------------------------
// JAX threefry2x32 (20 rounds) — verified bit-exact vs jax.random in R1.
// ---------------------------------------------------------------------------
__host__ __device__ inline void threefry2x32(unsigned k0, unsigned k1,
                                             unsigned x0, unsigned x1,
                                             unsigned* out0, unsigned* out1) {
  unsigned ks0 = k0, ks1 = k1, ks2 = k0 ^ k1 ^ 0x1BD11BDAu;
  x0 += ks0; x1 += ks1;
#define TF_ROUND(r) { x0 += x1; x1 = (x1 << (r)) | (x1 >> (32 - (r))); x1 ^= x0; }
  TF_ROUND(13) TF_ROUND(15) TF_ROUND(26) TF_ROUND(6)
  x0 += ks1; x1 += ks2 + 1u;
  TF_ROUND(17) TF_ROUND(29) TF_ROUND(16) TF_ROUND(24)
  x0 += ks2; x1 += ks0 + 2u;
  TF_ROUND(13) TF_ROUND(15) TF_ROUND(26) TF_ROUND(6)
  x0 += ks0; x1 += ks1 + 3u;
  TF_ROUND(17) TF_ROUND(29) TF_ROUND(16) TF_ROUND(24)
  x0 += ks1; x1 += ks2 + 4u;
  TF_ROUND(13) TF_ROUND(15) TF_ROUND(26) TF_ROUND(6)
  x0 += ks2; x1 += ks0 + 5u;
#undef TF_ROUND
  *out0 = x0; *out1 = x1;
}

__device__ inline float jax_uniform01(unsigned key0, unsigned key1, unsigned i) {
  unsigned o0, o1;
  threefry2x32(key0, key1, 0u, i, &o0, &o1);
  unsigned bits = o0 ^ o1;
  return __uint_as_float((bits >> 9) | 0x3f800000u) - 1.0f;
}

__device__ inline unsigned short f2bf(float f) {
  unsigned u = __float_as_uint(f);
  u += 0x7fffu + ((u >> 16) & 1u);   // round-to-nearest-even
  return (unsigned short)(u >> 16);
}

__device__ inline float bf2f(unsigned short b) {
  return __uint_as_float(((unsigned)b) << 16);
}

// ---------------------------------------------------------------------------
// k_init: zero deg + convert W1,W2 -> transposed bf16, one launch
// ---------------------------------------------------------------------------
__global__ __launch_bounds__(256) void k_init(int* __restrict__ deg, int n,
                                              const float* __restrict__ W1,
                                              unsigned short* __restrict__ W1T,
                                              const float* __restrict__ W2,
                                              unsigned short* __restrict__ W2T) {
  const int S1 = 512 * 256, S2 = 256 * 128;
  int idx = blockIdx.x * 256 + threadIdx.x;
  if (idx < n) { deg[idx] = 0; return; }
  idx -= n;
  if (idx < S1) {
    int k = idx / 256, c = idx % 256;
    W1T[(size_t)c * 512 + k] = f2bf(W1[idx]);
    return;
  }
  idx -= S1;
  if (idx < S2) {
    int k = idx / 128, c = idx % 128;
    W2T[(size_t)c * 256 + k] = f2bf(W2[idx]);
  }
}

__global__ void k_deg(const int* __restrict__ ei, int E, int* __restrict__ deg) {
  int e = blockIdx.x * blockDim.x + threadIdx.x;
  if (e >= E) return;
  atomicAdd(&deg[ei[E + e]], 1);
}

// Phase A: per-256-block sums
__global__ __launch_bounds__(256) void k_bsum(const int* __restrict__ deg,
                                              int* __restrict__ bsum, int n) {
  int i = blockIdx.x * 256 + threadIdx.x;
  int v = (i < n) ? deg[i] : 0;
#pragma unroll
  for (int o = 32; o; o >>= 1) v += __shfl_down(v, o);
  __shared__ int ws[4];
  if ((threadIdx.x & 63) == 0) ws[threadIdx.x >> 6] = v;
  __syncthreads();
  if (threadIdx.x == 0) bsum[blockIdx.x] = ws[0] + ws[1] + ws[2] + ws[3];
}

// Phase B+C fused: each block reduces its own prefix of bsum (nb<=128),
// then intra-block scan -> off/cur/dinv
__global__ __launch_bounds__(256) void k_scatter2(const int* __restrict__ deg,
                                                  const int* __restrict__ bsum,
                                                  int* __restrict__ off, int* __restrict__ cur,
                                                  float* __restrict__ dinv, int n) {
  int i = blockIdx.x * 256 + threadIdx.x;
  int lane = threadIdx.x & 63, w = threadIdx.x >> 6;
  // block base = sum of bsum[k], k < blockIdx.x (redundant per wave, cheap)
  int pb = 0;
  for (int k = lane; k < blockIdx.x; k += 64) pb += bsum[k];
#pragma unroll
  for (int o = 32; o; o >>= 1) pb += __shfl_xor(pb, o);

  int d = (i < n) ? deg[i] : 0;
  int inc = d;
#pragma unroll
  for (int o = 1; o < 64; o <<= 1) {
    int u = __shfl_up(inc, o);
    if (lane >= o) inc += u;
  }
  __shared__ int wsum[4];
  if (lane == 63) wsum[w] = inc;
  __syncthreads();
  int wbase = 0;
  for (int k = 0; k < w; ++k) wbase += wsum[k];
  int excl = inc - d + wbase + pb;
  if (i < n) {
    off[i] = excl;
    cur[i] = excl;
    dinv[i] = 1.0f / sqrtf((float)(d + 1));
    if (i == n - 1) off[n] = excl + d;
  }
}

// fill srcs + per-edge weight wgt = dinv[s]*dinv[d]
__global__ void k_fill_w(const int* __restrict__ ei, int E,
                         int* __restrict__ cur, int* __restrict__ srcs,
                         float* __restrict__ wgt, const float* __restrict__ dinv) {
  int e = blockIdx.x * blockDim.x + threadIdx.x;
  if (e >= E) return;
  int s = ei[e];
  int d = ei[E + e];
  int pos = atomicAdd(&cur[d], 1);
  srcs[pos] = s;
  wgt[pos] = dinv[s] * dinv[d];
}

// ---------------------------------------------------------------------------
// bf16 MFMA GEMM: C[M,N] = A[M,K] @ B[K,N], B given transposed bf16 [N,K].
// BM=64, BN=32*NF, BK=32; 4 waves (2x2), each 32 x (BN/2).
// ---------------------------------------------------------------------------
template <int NF, bool AF32, bool OBF>
__global__ __launch_bounds__(256) void k_gemm_mfma(const void* __restrict__ Ap,
                                                   const unsigned short* __restrict__ BT,
                                                   void* __restrict__ Cp,
                                                   int M, int N, int K) {
  constexpr int BN = 32 * NF;
  __shared__ unsigned short As[64][40];   // 80B rows: exact 2-way (free) on b128 reads
  __shared__ unsigned short Bs[BN][40];
  const int tid = threadIdx.x;
  const int row0 = blockIdx.y * 64;
  const int col0 = blockIdx.x * BN;
  const int w = tid >> 6, lane = tid & 63;
  const int wm = w >> 1, wn = w & 1;
  const int lr = lane & 15, lk = lane >> 4;

  f32x4 acc[2][NF];
#pragma unroll
  for (int mi = 0; mi < 2; ++mi)
#pragma unroll
    for (int ni = 0; ni < NF; ++ni) acc[mi][ni] = (f32x4)0.0f;

  const int ar = tid >> 2;            // A row 0..63
  const int aseg = (tid & 3) * 8;     // k offset within BK

  for (int k0 = 0; k0 < K; k0 += 32) {
    // ---- stage A (64 x 32 bf16) ----
    {
      int grow = row0 + ar;
      ushort8 av = (ushort8)0;
      if (grow < M) {
        if (AF32) {
          const float* A = (const float*)Ap;
          const float* p = &A[(size_t)grow * K + k0 + aseg];
          float4 v0 = *(const float4*)p;
          float4 v1 = *(const float4*)(p + 4);
          av[0] = f2bf(v0.x); av[1] = f2bf(v0.y); av[2] = f2bf(v0.z); av[3] = f2bf(v0.w);
          av[4] = f2bf(v1.x); av[5] = f2bf(v1.y); av[6] = f2bf(v1.z); av[7] = f2bf(v1.w);
        } else {
          const unsigned short* A = (const unsigned short*)Ap;
          av = *(const ushort8*)&A[(size_t)grow * K + k0 + aseg];
        }
      }
      *(ushort8*)&As[ar][aseg] = av;
    }
    // ---- stage B (BN rows of BT x 32) ----
#pragma unroll
    for (int p = 0; p < BN / 64; ++p) {
      int u = tid + p * 256;
      int br = u >> 2;
      int bseg = (u & 3) * 8;
      ushort8 bv = *(const ushort8*)&BT[(size_t)(col0 + br) * K + k0 + bseg];
      *(ushort8*)&Bs[br][bseg] = bv;
    }
    __syncthreads();

    short8 a[2], b[NF];
#pragma unroll
    for (int mi = 0; mi < 2; ++mi)
      a[mi] = *(const short8*)&As[wm * 32 + mi * 16 + lr][lk * 8];
#pragma unroll
    for (int ni = 0; ni < NF; ++ni)
      b[ni] = *(const short8*)&Bs[wn * (BN / 2) + ni * 16 + lr][lk * 8];
#pragma unroll
    for (int mi = 0; mi < 2; ++mi)
#pragma unroll
      for (int ni = 0; ni < NF; ++ni)
        acc[mi][ni] = __builtin_amdgcn_mfma_f32_16x16x32_bf16(a[mi], b[ni], acc[mi][ni], 0, 0, 0);
    __syncthreads();
  }

  // epilogue: C/D layout col=lane&15, row=(lane>>4)*4+reg  [m89-verified]
#pragma unroll
  for (int mi = 0; mi < 2; ++mi) {
    int rbase = row0 + wm * 32 + mi * 16 + lk * 4;
#pragma unroll
    for (int j = 0; j < 4; ++j) {
      int row = rbase + j;
      if (row < M) {
#pragma unroll
        for (int ni = 0; ni < NF; ++ni) {
          int col = col0 + wn * (BN / 2) + ni * 16 + lr;
          if (OBF) {
            ((unsigned short*)Cp)[(size_t)row * N + col] = f2bf(acc[mi][ni][j]);
          } else {
            ((float*)Cp)[(size_t)row * N + col] = acc[mi][ni][j];
          }
        }
      }
    }
  }
}

// ---------------------------------------------------------------------------
// fp32 tiled GEMM (layer 3 only, N=10)
// ---------------------------------------------------------------------------
__global__ __launch_bounds__(256) void k_gemm(const float* __restrict__ A,
                                              const float* __restrict__ B,
                                              float* __restrict__ C,
                                              int M, int N, int K) {
  __shared__ float As[64][17];
  __shared__ float Bs[16][64];
  const int tid = threadIdx.x;
  const int tx = tid & 15, ty = tid >> 4;
  const int row0 = blockIdx.y * 64, col0 = blockIdx.x * 64;
  const int am = tid >> 2;
  const int aq = (tid & 3) * 4;
  const int bk = tid >> 4;
  const int bg = (tid & 15) * 4;
  const bool nvec = ((N & 3) == 0);
  float acc[4][4] = {{0.f}};

  for (int k0 = 0; k0 < K; k0 += 16) {
    {
      int row = row0 + am;
      if (row < M) {
        const float4 v = *reinterpret_cast<const float4*>(&A[(size_t)row * K + k0 + aq]);
        As[am][aq + 0] = v.x; As[am][aq + 1] = v.y;
        As[am][aq + 2] = v.z; As[am][aq + 3] = v.w;
      } else {
        As[am][aq + 0] = 0.f; As[am][aq + 1] = 0.f;
        As[am][aq + 2] = 0.f; As[am][aq + 3] = 0.f;
      }
    }
    {
      int krow = k0 + bk;
      if (nvec && (col0 + bg + 4 <= N)) {
        const float4 v = *reinterpret_cast<const float4*>(&B[(size_t)krow * N + col0 + bg]);
        Bs[bk][bg + 0] = v.x; Bs[bk][bg + 1] = v.y;
        Bs[bk][bg + 2] = v.z; Bs[bk][bg + 3] = v.w;
      } else {
        for (int j = 0; j < 4; ++j) {
          int col = col0 + bg + j;
          Bs[bk][bg + j] = (col < N) ? B[(size_t)krow * N + col] : 0.f;
        }
      }
    }
    __syncthreads();
#pragma unroll
    for (int kk = 0; kk < 16; ++kk) {
      float a0 = As[ty * 4 + 0][kk];
      float a1 = As[ty * 4 + 1][kk];
      float a2 = As[ty * 4 + 2][kk];
      float a3 = As[ty * 4 + 3][kk];
      float4 bv = *reinterpret_cast<const float4*>(&Bs[kk][tx * 4]);
      acc[0][0] += a0 * bv.x; acc[0][1] += a0 * bv.y; acc[0][2] += a0 * bv.z; acc[0][3] += a0 * bv.w;
      acc[1][0] += a1 * bv.x; acc[1][1] += a1 * bv.y; acc[1][2] += a1 * bv.z; acc[1][3] += a1 * bv.w;
      acc[2][0] += a2 * bv.x; acc[2][1] += a2 * bv.y; acc[2][2] += a2 * bv.z; acc[2][3] += a2 * bv.w;
      acc[3][0] += a3 * bv.x; acc[3][1] += a3 * bv.y; acc[3][2] += a3 * bv.z; acc[3][3] += a3 * bv.w;
    }
    __syncthreads();
  }

  for (int i = 0; i < 4; ++i) {
    int row = row0 + ty * 4 + i;
    if (row >= M) continue;
    for (int j = 0; j < 4; ++j) {
      int col = col0 + tx * 4 + j;
      if (col < N) C[(size_t)row * N + col] = acc[i][j];
    }
  }
}

// ---------------------------------------------------------------------------
// Wave-per-node GCN aggregation over bf16 h (+bias, relu, jax dropout).
// C bf16 elems per lane (F = 64*C); 4 nodes per 256-thread block; unroll x8.
// Edge weights precomputed (streaming read).
// ---------------------------------------------------------------------------
template <int C, bool OBF>
__global__ __launch_bounds__(256) void k_agg_bf(const unsigned short* __restrict__ h,
                                                void* __restrict__ outv,
                                                const int* __restrict__ off,
                                                const int* __restrict__ srcs,
                                                const float* __restrict__ wgt,
                                                const float* __restrict__ dinv,
                                                const float* __restrict__ bias,
                                                unsigned key0, unsigned key1, int n) {
  typedef __attribute__((ext_vector_type(C))) unsigned short ushortC;
  const int node = blockIdx.x * (blockDim.x >> 6) + (threadIdx.x >> 6);
  if (node >= n) return;
  const int lane = threadIdx.x & 63;
  const int F = 64 * C;
  const float dv = dinv[node];

  float acc[C];
  {
    ushortC r = *(const ushortC*)(h + (size_t)node * F + lane * C);
    float wv = dv * dv;
#pragma unroll
    for (int j = 0; j < C; ++j) acc[j] = bf2f(r[j]) * wv;
  }
  int e = off[node];
  const int e1 = off[node + 1];
  for (; e + 8 <= e1; e += 8) {
    int s[8];
    float wv[8];
    ushortC r[8];
#pragma unroll
    for (int q = 0; q < 8; ++q) s[q] = srcs[e + q];
#pragma unroll
    for (int q = 0; q < 8; ++q) wv[q] = wgt[e + q];
#pragma unroll
    for (int q = 0; q < 8; ++q) r[q] = *(const ushortC*)(h + (size_t)s[q] * F + lane * C);
#pragma unroll
    for (int q = 0; q < 8; ++q)
#pragma unroll
      for (int j = 0; j < C; ++j) acc[j] += bf2f(r[q][j]) * wv[q];
  }
  for (; e < e1; ++e) {
    int s = srcs[e];
    float wv = wgt[e];
    ushortC r = *(const ushortC*)(h + (size_t)s * F + lane * C);
#pragma unroll
    for (int j = 0; j < C; ++j) acc[j] += bf2f(r[j]) * wv;
  }
#pragma unroll
  for (int j = 0; j < C; ++j) {
    float v = acc[j] + bias[lane * C + j];
    v = fmaxf(v, 0.0f);
    unsigned i = (unsigned)(node * F + lane * C + j);
    float u = jax_uniform01(key0, key1, i);
    v = (u < 0.8f) ? (v * 1.25f) : 0.0f;
    acc[j] = v;
  }
  if (OBF) {
    unsigned short* op = (unsigned short*)outv + (size_t)node * F + lane * C;
#pragma unroll
    for (int j = 0; j < C; ++j) op[j] = f2bf(acc[j]);
  } else {
    float* op = (float*)outv + (size_t)node * F + lane * C;
#pragma unroll
    for (int j = 0; j < C; ++j) op[j] = acc[j];
  }
}

// ---------------------------------------------------------------------------
// layer 3: wave-per-node aggregate (10-dim) + bias + log_softmax.
// ---------------------------------------------------------------------------
__global__ __launch_bounds__(256) void k_agg3_lsm_v2(const float* __restrict__ h,
                                                     float* __restrict__ out,
                                                     const int* __restrict__ off,
                                                     const int* __restrict__ srcs,
                                                     const float* __restrict__ wgt,
                                                     const float* __restrict__ dinv,
                                                     const float* __restrict__ b,
                                                     int n) {
  const int node = blockIdx.x * 4 + (threadIdx.x >> 6);
  if (node >= n) return;
  const int lane = threadIdx.x & 63;
  const bool act = (lane < 10);
  const float dv = dinv[node];

  float acc = 0.0f;
  if (act) acc = h[(size_t)node * 10 + lane] * dv * dv;
  int e = off[node];
  const int e1 = off[node + 1];
  for (; e + 4 <= e1; e += 4) {
    int s0 = srcs[e + 0], s1 = srcs[e + 1], s2 = srcs[e + 2], s3 = srcs[e + 3];
    float w0 = wgt[e + 0], w1 = wgt[e + 1], w2 = wgt[e + 2], w3 = wgt[e + 3];
    if (act) {
      acc += h[(size_t)s0 * 10 + lane] * w0 + h[(size_t)s1 * 10 + lane] * w1 +
             h[(size_t)s2 * 10 + lane] * w2 + h[(size_t)s3 * 10 + lane] * w3;
    }
  }
  for (; e < e1; ++e) {
    int s = srcs[e];
    float w = wgt[e];
    if (act) acc += h[(size_t)s * 10 + lane] * w;
  }
  float v = act ? (acc + b[lane]) : -1e30f;
  float m = v;
#pragma unroll
  for (int o = 32; o; o >>= 1) m = fmaxf(m, __shfl_xor(m, o));
  float p = act ? expf(v - m) : 0.0f;
  float ssum = p;
#pragma unroll
  for (int o = 32; o; o >>= 1) ssum += __shfl_xor(ssum, o);
  float lse = m + logf(ssum);
  if (act) out[(size_t)node * 10 + lane] = v - lse;
}

// ---------------------------------------------------------------------------
extern "C" void kernel_launch(void* const* d_in, const int* in_sizes, int n_in,
                              void* d_out, int out_size, void* d_ws, size_t ws_size,
                              hipStream_t stream) {
  const float* x  = (const float*)d_in[0];
  const int*   ei = (const int*)d_in[1];
  const float* W1 = (const float*)d_in[2];
  const float* b1 = (const float*)d_in[3];
  const float* W2 = (const float*)d_in[4];
  const float* b2 = (const float*)d_in[5];
  const float* W3 = (const float*)d_in[6];
  const float* b3 = (const float*)d_in[7];
  float* out = (float*)d_out;

  const int N = 20000;
  const int E = in_sizes[1] / 2;
  const int D1 = 256, D2 = 128;
  const int NB = (N + 255) / 256;   // 79 scan blocks

  char* ws = (char*)d_ws;
  auto carve = [&](size_t bytes) -> char* {
    char* p = ws;
    ws += (bytes + 255) & ~(size_t)255;
    return p;
  };
  int*   deg  = (int*)carve((size_t)N * 4);
  int*   off  = (int*)carve((size_t)(N + 1) * 4);
  int*   cur  = (int*)carve((size_t)N * 4);
  float* dinv = (float*)carve((size_t)N * 4);
  int*   bsum = (int*)carve((size_t)128 * 4);
  int*   srcs = (int*)carve((size_t)E * 4);
  float* wgt  = (float*)carve((size_t)E * 4);
  unsigned short* W1T = (unsigned short*)carve((size_t)D1 * 512 * 2);
  unsigned short* W2T = (unsigned short*)carve((size_t)D2 * D1 * 2);
  unsigned short* bufHb = (unsigned short*)carve((size_t)N * D1 * 2);   // h1(bf16), then h2(bf16)
  unsigned short* bufA_bf = (unsigned short*)carve((size_t)N * D1 * 2); // agg1 bf16; agg2 fp32 reuse
  float* bufA2 = (float*)bufA_bf;
  float* bufH3 = (float*)carve((size_t)N * 10 * 4);                     // h3 fp32

  unsigned dk1_0, dk1_1, dk2_0, dk2_1;
  threefry2x32(0u, 1u, 0u, 0u, &dk1_0, &dk1_1);
  threefry2x32(0u, 1u, 0u, 1u, &dk2_0, &dk2_1);

  // graph prep + weight conversion (11 dispatches total)
  const int INIT_ITEMS = N + 512 * 256 + 256 * 128;
  k_init<<<(INIT_ITEMS + 255) / 256, 256, 0, stream>>>(deg, N, W1, W1T, W2, W2T);
  k_deg<<<(E + 255) / 256, 256, 0, stream>>>(ei, E, deg);
  k_bsum<<<NB, 256, 0, stream>>>(deg, bsum, N);
  k_scatter2<<<NB, 256, 0, stream>>>(deg, bsum, off, cur, dinv, N);
  k_fill_w<<<(E + 255) / 256, 256, 0, stream>>>(ei, E, cur, srcs, wgt, dinv);

  // layer 1: h1(bf16) = x @ W1 ; agg + b1 + relu + dropout(dk1) -> bf16
  k_gemm_mfma<4, true, true><<<dim3(D1 / 128, (N + 63) / 64), 256, 0, stream>>>(x, W1T, bufHb, N, D1, 512);
  k_agg_bf<4, true><<<(N + 3) / 4, 256, 0, stream>>>(bufHb, bufA_bf, off, srcs, wgt, dinv, b1, dk1_0, dk1_1, N);

  // layer 2: h2(bf16) = a1 @ W2 ; agg + b2 + relu + dropout(dk2) -> fp32
  k_gemm_mfma<4, false, true><<<dim3(D2 / 128, (N + 63) / 64), 256, 0, stream>>>(bufA_bf, W2T, bufHb, N, D2, D1);
  k_agg_bf<2, false><<<(N + 3) / 4, 256, 0, stream>>>(bufHb, bufA2, off, srcs, wgt, dinv, b2, dk2_0, dk2_1, N);

  // layer 3 (fp32, N=10) + wave-parallel agg + log_softmax
  k_gemm<<<dim3(1, (N + 63) / 64), 256, 0, stream>>>(bufA2, W3, bufH3, N, 10, D2);
  k_agg3_lsm_v2<<<(N + 3) / 4, 256, 0, stream>>>(bufH3, out, off, srcs, wgt, dinv, b3, N);
}

// Round 7
// 151.766 us; speedup vs baseline: 1.3461x; 1.0558x over previous
//
#include <hip/hip_runtime.h>
#include <hip/hip_bf16.h>
#include <math.h>

typedef __attribute__((ext_vector_type(8))) short short8;
typedef __attribute__((ext_vector_type(8))) unsigned short ushort8;
typedef __attribute__((ext_vector_type(4))) unsigned short ushort4v;
typedef __attribute__((ext_vector_type(4))) float f32x4;

// ---------------------------------------------------------------------------
// JAX threefry2x32 (20 rounds) — verified bit-exact vs jax.random in R1.
// ---------------------------------------------------------------------------
__host__ __device__ inline void threefry2x32(unsigned k0, unsigned k1,
                                             unsigned x0, unsigned x1,
                                             unsigned* out0, unsigned* out1) {
  unsigned ks0 = k0, ks1 = k1, ks2 = k0 ^ k1 ^ 0x1BD11BDAu;
  x0 += ks0; x1 += ks1;
#define TF_ROUND(r) { x0 += x1; x1 = (x1 << (r)) | (x1 >> (32 - (r))); x1 ^= x0; }
  TF_ROUND(13) TF_ROUND(15) TF_ROUND(26) TF_ROUND(6)
  x0 += ks1; x1 += ks2 + 1u;
  TF_ROUND(17) TF_ROUND(29) TF_ROUND(16) TF_ROUND(24)
  x0 += ks2; x1 += ks0 + 2u;
  TF_ROUND(13) TF_ROUND(15) TF_ROUND(26) TF_ROUND(6)
  x0 += ks0; x1 += ks1 + 3u;
  TF_ROUND(17) TF_ROUND(29) TF_ROUND(16) TF_ROUND(24)
  x0 += ks1; x1 += ks2 + 4u;
  TF_ROUND(13) TF_ROUND(15) TF_ROUND(26) TF_ROUND(6)
  x0 += ks2; x1 += ks0 + 5u;
#undef TF_ROUND
  *out0 = x0; *out1 = x1;
}

__device__ inline float jax_uniform01(unsigned key0, unsigned key1, unsigned i) {
  unsigned o0, o1;
  threefry2x32(key0, key1, 0u, i, &o0, &o1);
  unsigned bits = o0 ^ o1;
  return __uint_as_float((bits >> 9) | 0x3f800000u) - 1.0f;
}

__device__ inline unsigned short f2bf(float f) {
  unsigned u = __float_as_uint(f);
  u += 0x7fffu + ((u >> 16) & 1u);   // round-to-nearest-even
  return (unsigned short)(u >> 16);
}

__device__ inline float bf2f(unsigned short b) {
  return __uint_as_float(((unsigned)b) << 16);
}

// ---------------------------------------------------------------------------
// k_init: zero deg + convert W1,W2 -> transposed bf16, one launch
// ---------------------------------------------------------------------------
__global__ __launch_bounds__(256) void k_init(int* __restrict__ deg, int n,
                                              const float* __restrict__ W1,
                                              unsigned short* __restrict__ W1T,
                                              const float* __restrict__ W2,
                                              unsigned short* __restrict__ W2T) {
  const int S1 = 512 * 256, S2 = 256 * 128;
  int idx = blockIdx.x * 256 + threadIdx.x;
  if (idx < n) { deg[idx] = 0; return; }
  idx -= n;
  if (idx < S1) {
    int k = idx / 256, c = idx % 256;
    W1T[(size_t)c * 512 + k] = f2bf(W1[idx]);
    return;
  }
  idx -= S1;
  if (idx < S2) {
    int k = idx / 128, c = idx % 128;
    W2T[(size_t)c * 256 + k] = f2bf(W2[idx]);
  }
}

__global__ void k_deg(const int* __restrict__ ei, int E, int* __restrict__ deg) {
  int e = blockIdx.x * blockDim.x + threadIdx.x;
  if (e >= E) return;
  atomicAdd(&deg[ei[E + e]], 1);
}

// Phase A: per-256-block sums
__global__ __launch_bounds__(256) void k_bsum(const int* __restrict__ deg,
                                              int* __restrict__ bsum, int n) {
  int i = blockIdx.x * 256 + threadIdx.x;
  int v = (i < n) ? deg[i] : 0;
#pragma unroll
  for (int o = 32; o; o >>= 1) v += __shfl_down(v, o);
  __shared__ int ws[4];
  if ((threadIdx.x & 63) == 0) ws[threadIdx.x >> 6] = v;
  __syncthreads();
  if (threadIdx.x == 0) bsum[blockIdx.x] = ws[0] + ws[1] + ws[2] + ws[3];
}

// Phase B+C fused: block base via redundant bsum prefix reduce, then
// intra-block scan -> off/cur/dinv
__global__ __launch_bounds__(256) void k_scatter2(const int* __restrict__ deg,
                                                  const int* __restrict__ bsum,
                                                  int* __restrict__ off, int* __restrict__ cur,
                                                  float* __restrict__ dinv, int n) {
  int i = blockIdx.x * 256 + threadIdx.x;
  int lane = threadIdx.x & 63, w = threadIdx.x >> 6;
  int pb = 0;
  for (int k = lane; k < blockIdx.x; k += 64) pb += bsum[k];
#pragma unroll
  for (int o = 32; o; o >>= 1) pb += __shfl_xor(pb, o);

  int d = (i < n) ? deg[i] : 0;
  int inc = d;
#pragma unroll
  for (int o = 1; o < 64; o <<= 1) {
    int u = __shfl_up(inc, o);
    if (lane >= o) inc += u;
  }
  __shared__ int wsum[4];
  if (lane == 63) wsum[w] = inc;
  __syncthreads();
  int wbase = 0;
  for (int k = 0; k < w; ++k) wbase += wsum[k];
  int excl = inc - d + wbase + pb;
  if (i < n) {
    off[i] = excl;
    cur[i] = excl;
    dinv[i] = 1.0f / sqrtf((float)(d + 1));
    if (i == n - 1) off[n] = excl + d;
  }
}

// fill srcs + per-edge weight wgt = dinv[s]*dinv[d]
__global__ void k_fill_w(const int* __restrict__ ei, int E,
                         int* __restrict__ cur, int* __restrict__ srcs,
                         float* __restrict__ wgt, const float* __restrict__ dinv) {
  int e = blockIdx.x * blockDim.x + threadIdx.x;
  if (e >= E) return;
  int s = ei[e];
  int d = ei[E + e];
  int pos = atomicAdd(&cur[d], 1);
  srcs[pos] = s;
  wgt[pos] = dinv[s] * dinv[d];
}

// ---------------------------------------------------------------------------
// bf16 MFMA GEMM, BM=32 tiles: C[M,N] = A[M,K] @ B[K,N], B transposed bf16 [N,K].
// 4 waves side-by-side along N; each wave 32 x (BN/4); grid (1, M/32).
// ---------------------------------------------------------------------------
template <int BN, bool AF32, bool OBF>
__global__ __launch_bounds__(256) void k_gemm_mfma(const void* __restrict__ Ap,
                                                   const unsigned short* __restrict__ BT,
                                                   void* __restrict__ Cp,
                                                   int M, int N, int K) {
  constexpr int WCOLS = BN / 4;       // cols per wave
  constexpr int NFW = WCOLS / 16;     // n-frags per wave
  __shared__ unsigned short As[32][40];   // 80B rows: 2-way-only conflicts (free)
  __shared__ unsigned short Bs[BN][40];
  const int tid = threadIdx.x;
  const int row0 = blockIdx.y * 32;
  const int col0 = blockIdx.x * BN;
  const int wn = tid >> 6, lane = tid & 63;
  const int lr = lane & 15, lk = lane >> 4;

  f32x4 acc[2][NFW];
#pragma unroll
  for (int mi = 0; mi < 2; ++mi)
#pragma unroll
    for (int ni = 0; ni < NFW; ++ni) acc[mi][ni] = (f32x4)0.0f;

  const int ar = tid >> 3;            // A row 0..31
  const int aseg = (tid & 7) * 4;     // 4 elems per thread

  for (int k0 = 0; k0 < K; k0 += 32) {
    // ---- stage A (32 x 32 bf16), 4 elems/thread ----
    {
      int grow = row0 + ar;
      unsigned short a4[4] = {0, 0, 0, 0};
      if (grow < M) {
        if (AF32) {
          const float* A = (const float*)Ap;
          float4 v = *(const float4*)&A[(size_t)grow * K + k0 + aseg];
          a4[0] = f2bf(v.x); a4[1] = f2bf(v.y); a4[2] = f2bf(v.z); a4[3] = f2bf(v.w);
        } else {
          const unsigned short* A = (const unsigned short*)Ap;
          ushort4v v = *(const ushort4v*)&A[(size_t)grow * K + k0 + aseg];
          a4[0] = v[0]; a4[1] = v[1]; a4[2] = v[2]; a4[3] = v[3];
        }
      }
      *(ushort4v*)&As[ar][aseg] = *(ushort4v*)a4;
    }
    // ---- stage B (BN rows of BT x 32), ushort8 per slot ----
#pragma unroll
    for (int p = 0; p < BN / 64; ++p) {
      int u = tid + p * 256;
      int br = u >> 2;
      int bseg = (u & 3) * 8;
      ushort8 bv = *(const ushort8*)&BT[(size_t)(col0 + br) * K + k0 + bseg];
      *(ushort8*)&Bs[br][bseg] = bv;
    }
    __syncthreads();

    short8 a[2], b[NFW];
#pragma unroll
    for (int mi = 0; mi < 2; ++mi)
      a[mi] = *(const short8*)&As[mi * 16 + lr][lk * 8];
#pragma unroll
    for (int ni = 0; ni < NFW; ++ni)
      b[ni] = *(const short8*)&Bs[wn * WCOLS + ni * 16 + lr][lk * 8];
#pragma unroll
    for (int mi = 0; mi < 2; ++mi)
#pragma unroll
      for (int ni = 0; ni < NFW; ++ni)
        acc[mi][ni] = __builtin_amdgcn_mfma_f32_16x16x32_bf16(a[mi], b[ni], acc[mi][ni], 0, 0, 0);
    __syncthreads();
  }

  // epilogue: C/D layout col=lane&15, row=(lane>>4)*4+reg  [m89-verified]
#pragma unroll
  for (int mi = 0; mi < 2; ++mi) {
    int rbase = row0 + mi * 16 + lk * 4;
#pragma unroll
    for (int j = 0; j < 4; ++j) {
      int row = rbase + j;
      if (row < M) {
#pragma unroll
        for (int ni = 0; ni < NFW; ++ni) {
          int col = col0 + wn * WCOLS + ni * 16 + lr;
          if (OBF) {
            ((unsigned short*)Cp)[(size_t)row * N + col] = f2bf(acc[mi][ni][j]);
          } else {
            ((float*)Cp)[(size_t)row * N + col] = acc[mi][ni][j];
          }
        }
      }
    }
  }
}

// ---------------------------------------------------------------------------
// Wave-per-node GCN aggregation over bf16 h (+bias, relu, jax dropout).
// C bf16 elems per lane (F = 64*C); 4 nodes per 256-thread block; unroll x8.
// ---------------------------------------------------------------------------
template <int C, bool OBF>
__global__ __launch_bounds__(256) void k_agg_bf(const unsigned short* __restrict__ h,
                                                void* __restrict__ outv,
                                                const int* __restrict__ off,
                                                const int* __restrict__ srcs,
                                                const float* __restrict__ wgt,
                                                const float* __restrict__ dinv,
                                                const float* __restrict__ bias,
                                                unsigned key0, unsigned key1, int n) {
  typedef __attribute__((ext_vector_type(C))) unsigned short ushortC;
  const int node = blockIdx.x * (blockDim.x >> 6) + (threadIdx.x >> 6);
  if (node >= n) return;
  const int lane = threadIdx.x & 63;
  const int F = 64 * C;
  const float dv = dinv[node];

  float acc[C];
  {
    ushortC r = *(const ushortC*)(h + (size_t)node * F + lane * C);
    float wv = dv * dv;
#pragma unroll
    for (int j = 0; j < C; ++j) acc[j] = bf2f(r[j]) * wv;
  }
  int e = off[node];
  const int e1 = off[node + 1];
  for (; e + 8 <= e1; e += 8) {
    int s[8];
    float wv[8];
    ushortC r[8];
#pragma unroll
    for (int q = 0; q < 8; ++q) s[q] = srcs[e + q];
#pragma unroll
    for (int q = 0; q < 8; ++q) wv[q] = wgt[e + q];
#pragma unroll
    for (int q = 0; q < 8; ++q) r[q] = *(const ushortC*)(h + (size_t)s[q] * F + lane * C);
#pragma unroll
    for (int q = 0; q < 8; ++q)
#pragma unroll
      for (int j = 0; j < C; ++j) acc[j] += bf2f(r[q][j]) * wv[q];
  }
  for (; e < e1; ++e) {
    int s = srcs[e];
    float wv = wgt[e];
    ushortC r = *(const ushortC*)(h + (size_t)s * F + lane * C);
#pragma unroll
    for (int j = 0; j < C; ++j) acc[j] += bf2f(r[j]) * wv;
  }
#pragma unroll
  for (int j = 0; j < C; ++j) {
    float v = acc[j] + bias[lane * C + j];
    v = fmaxf(v, 0.0f);
    unsigned i = (unsigned)(node * F + lane * C + j);
    float u = jax_uniform01(key0, key1, i);
    v = (u < 0.8f) ? (v * 1.25f) : 0.0f;
    acc[j] = v;
  }
  if (OBF) {
    unsigned short* op = (unsigned short*)outv + (size_t)node * F + lane * C;
#pragma unroll
    for (int j = 0; j < C; ++j) op[j] = f2bf(acc[j]);
  } else {
    float* op = (float*)outv + (size_t)node * F + lane * C;
#pragma unroll
    for (int j = 0; j < C; ++j) op[j] = acc[j];
  }
}

// ---------------------------------------------------------------------------
// agg2 + layer-3 GEMM fused: aggregate h2 (bf16, 128 feat), bias+relu+dropout
// in regs, then h3[node][0..9] = a2_row @ W3 via per-lane W3 rows + butterfly.
// ---------------------------------------------------------------------------
__global__ __launch_bounds__(256) void k_agg2_g3(const unsigned short* __restrict__ h,
                                                 float* __restrict__ h3,
                                                 const int* __restrict__ off,
                                                 const int* __restrict__ srcs,
                                                 const float* __restrict__ wgt,
                                                 const float* __restrict__ dinv,
                                                 const float* __restrict__ b2,
                                                 const float* __restrict__ W3,
                                                 unsigned key0, unsigned key1, int n) {
  const int node = blockIdx.x * 4 + (threadIdx.x >> 6);
  if (node >= n) return;
  const int lane = threadIdx.x & 63;

  // W3 rows 2*lane and 2*lane+1 -> 20 regs (coalesced, L2-hot)
  float w3a[10], w3b[10];
  {
    const float4* p = (const float4*)(W3 + lane * 20);
    float4 v0 = p[0], v1 = p[1], v2 = p[2], v3 = p[3], v4 = p[4];
    w3a[0] = v0.x; w3a[1] = v0.y; w3a[2] = v0.z; w3a[3] = v0.w;
    w3a[4] = v1.x; w3a[5] = v1.y; w3a[6] = v1.z; w3a[7] = v1.w;
    w3a[8] = v2.x; w3a[9] = v2.y;
    w3b[0] = v2.z; w3b[1] = v2.w;
    w3b[2] = v3.x; w3b[3] = v3.y; w3b[4] = v3.z; w3b[5] = v3.w;
    w3b[6] = v4.x; w3b[7] = v4.y; w3b[8] = v4.z; w3b[9] = v4.w;
  }

  const float dv = dinv[node];
  float acc0, acc1;
  {
    unsigned r = *(const unsigned*)(h + (size_t)node * 128 + lane * 2);
    float wv = dv * dv;
    acc0 = bf2f((unsigned short)(r & 0xffffu)) * wv;
    acc1 = bf2f((unsigned short)(r >> 16)) * wv;
  }
  int e = off[node];
  const int e1 = off[node + 1];
  for (; e + 8 <= e1; e += 8) {
    int s[8];
    float wv[8];
    unsigned r[8];
#pragma unroll
    for (int q = 0; q < 8; ++q) s[q] = srcs[e + q];
#pragma unroll
    for (int q = 0; q < 8; ++q) wv[q] = wgt[e + q];
#pragma unroll
    for (int q = 0; q < 8; ++q) r[q] = *(const unsigned*)(h + (size_t)s[q] * 128 + lane * 2);
#pragma unroll
    for (int q = 0; q < 8; ++q) {
      acc0 += bf2f((unsigned short)(r[q] & 0xffffu)) * wv[q];
      acc1 += bf2f((unsigned short)(r[q] >> 16)) * wv[q];
    }
  }
  for (; e < e1; ++e) {
    int s = srcs[e];
    float wv = wgt[e];
    unsigned r = *(const unsigned*)(h + (size_t)s * 128 + lane * 2);
    acc0 += bf2f((unsigned short)(r & 0xffffu)) * wv;
    acc1 += bf2f((unsigned short)(r >> 16)) * wv;
  }
  // bias + relu + dropout (dk2), flat index node*128 + lane*2 + j
  {
    float v = fmaxf(acc0 + b2[lane * 2], 0.0f);
    float u = jax_uniform01(key0, key1, (unsigned)(node * 128 + lane * 2));
    acc0 = (u < 0.8f) ? (v * 1.25f) : 0.0f;
  }
  {
    float v = fmaxf(acc1 + b2[lane * 2 + 1], 0.0f);
    float u = jax_uniform01(key0, key1, (unsigned)(node * 128 + lane * 2 + 1));
    acc1 = (u < 0.8f) ? (v * 1.25f) : 0.0f;
  }
  // layer-3 GEMM: h3[c] = sum_k a2[k] * W3[k][c]
  float myout = 0.0f;
#pragma unroll
  for (int c = 0; c < 10; ++c) {
    float part = acc0 * w3a[c] + acc1 * w3b[c];
#pragma unroll
    for (int o = 32; o; o >>= 1) part += __shfl_xor(part, o);
    if (lane == c) myout = part;
  }
  if (lane < 10) h3[(size_t)node * 10 + lane] = myout;
}

// ---------------------------------------------------------------------------
// layer 3: wave-per-node aggregate (10-dim) + bias + log_softmax.
// ---------------------------------------------------------------------------
__global__ __launch_bounds__(256) void k_agg3_lsm_v2(const float* __restrict__ h,
                                                     float* __restrict__ out,
                                                     const int* __restrict__ off,
                                                     const int* __restrict__ srcs,
                                                     const float* __restrict__ wgt,
                                                     const float* __restrict__ dinv,
                                                     const float* __restrict__ b,
                                                     int n) {
  const int node = blockIdx.x * 4 + (threadIdx.x >> 6);
  if (node >= n) return;
  const int lane = threadIdx.x & 63;
  const bool act = (lane < 10);
  const float dv = dinv[node];

  float acc = 0.0f;
  if (act) acc = h[(size_t)node * 10 + lane] * dv * dv;
  int e = off[node];
  const int e1 = off[node + 1];
  for (; e + 4 <= e1; e += 4) {
    int s0 = srcs[e + 0], s1 = srcs[e + 1], s2 = srcs[e + 2], s3 = srcs[e + 3];
    float w0 = wgt[e + 0], w1 = wgt[e + 1], w2 = wgt[e + 2], w3 = wgt[e + 3];
    if (act) {
      acc += h[(size_t)s0 * 10 + lane] * w0 + h[(size_t)s1 * 10 + lane] * w1 +
             h[(size_t)s2 * 10 + lane] * w2 + h[(size_t)s3 * 10 + lane] * w3;
    }
  }
  for (; e < e1; ++e) {
    int s = srcs[e];
    float w = wgt[e];
    if (act) acc += h[(size_t)s * 10 + lane] * w;
  }
  float v = act ? (acc + b[lane]) : -1e30f;
  float m = v;
#pragma unroll
  for (int o = 32; o; o >>= 1) m = fmaxf(m, __shfl_xor(m, o));
  float p = act ? expf(v - m) : 0.0f;
  float ssum = p;
#pragma unroll
  for (int o = 32; o; o >>= 1) ssum += __shfl_xor(ssum, o);
  float lse = m + logf(ssum);
  if (act) out[(size_t)node * 10 + lane] = v - lse;
}

// ---------------------------------------------------------------------------
extern "C" void kernel_launch(void* const* d_in, const int* in_sizes, int n_in,
                              void* d_out, int out_size, void* d_ws, size_t ws_size,
                              hipStream_t stream) {
  const float* x  = (const float*)d_in[0];
  const int*   ei = (const int*)d_in[1];
  const float* W1 = (const float*)d_in[2];
  const float* b1 = (const float*)d_in[3];
  const float* W2 = (const float*)d_in[4];
  const float* b2 = (const float*)d_in[5];
  const float* W3 = (const float*)d_in[6];
  const float* b3 = (const float*)d_in[7];
  float* out = (float*)d_out;

  const int N = 20000;
  const int E = in_sizes[1] / 2;
  const int D1 = 256, D2 = 128;
  const int NB = (N + 255) / 256;   // 79 scan blocks

  char* ws = (char*)d_ws;
  auto carve = [&](size_t bytes) -> char* {
    char* p = ws;
    ws += (bytes + 255) & ~(size_t)255;
    return p;
  };
  int*   deg  = (int*)carve((size_t)N * 4);
  int*   off  = (int*)carve((size_t)(N + 1) * 4);
  int*   cur  = (int*)carve((size_t)N * 4);
  float* dinv = (float*)carve((size_t)N * 4);
  int*   bsum = (int*)carve((size_t)128 * 4);
  int*   srcs = (int*)carve((size_t)E * 4);
  float* wgt  = (float*)carve((size_t)E * 4);
  unsigned short* W1T = (unsigned short*)carve((size_t)D1 * 512 * 2);
  unsigned short* W2T = (unsigned short*)carve((size_t)D2 * D1 * 2);
  unsigned short* bufHb = (unsigned short*)carve((size_t)N * D1 * 2);   // h1(bf16), then h2(bf16)
  unsigned short* bufA_bf = (unsigned short*)carve((size_t)N * D1 * 2); // a1 bf16
  float* bufH3 = (float*)carve((size_t)N * 10 * 4);                     // h3 fp32

  unsigned dk1_0, dk1_1, dk2_0, dk2_1;
  threefry2x32(0u, 1u, 0u, 0u, &dk1_0, &dk1_1);
  threefry2x32(0u, 1u, 0u, 1u, &dk2_0, &dk2_1);

  // graph prep + weight conversion (10 dispatches total)
  const int INIT_ITEMS = N + 512 * 256 + 256 * 128;
  k_init<<<(INIT_ITEMS + 255) / 256, 256, 0, stream>>>(deg, N, W1, W1T, W2, W2T);
  k_deg<<<(E + 255) / 256, 256, 0, stream>>>(ei, E, deg);
  k_bsum<<<NB, 256, 0, stream>>>(deg, bsum, N);
  k_scatter2<<<NB, 256, 0, stream>>>(deg, bsum, off, cur, dinv, N);
  k_fill_w<<<(E + 255) / 256, 256, 0, stream>>>(ei, E, cur, srcs, wgt, dinv);

  // layer 1: h1(bf16) = x @ W1 (single pass over x) ; agg -> a1 bf16
  k_gemm_mfma<256, true, true><<<dim3(1, N / 32), 256, 0, stream>>>(x, W1T, bufHb, N, D1, 512);
  k_agg_bf<4, true><<<(N + 3) / 4, 256, 0, stream>>>(bufHb, bufA_bf, off, srcs, wgt, dinv, b1, dk1_0, dk1_1, N);

  // layer 2: h2(bf16) = a1 @ W2 ; agg2 + gemm3 fused -> h3
  k_gemm_mfma<128, false, true><<<dim3(1, N / 32), 256, 0, stream>>>(bufA_bf, W2T, bufHb, N, D2, D1);
  k_agg2_g3<<<(N + 3) / 4, 256, 0, stream>>>(bufHb, bufH3, off, srcs, wgt, dinv, b2, W3, dk2_0, dk2_1, N);

  // layer 3 aggregation + log_softmax
  k_agg3_lsm_v2<<<(N + 3) / 4, 256, 0, stream>>>(bufH3, out, off, srcs, wgt, dinv, b3, N);
}